// Round 1
// baseline (280.318 us; speedup 1.0000x reference)
//
#include <hip/hip_runtime.h>
#include <hip/hip_bf16.h>

// LGM loss: logits/margin_logits [8192,10000] f32 + scalar likelihood.
// Write-bound: 655 MB of outputs -> ~104 us floor at 6.3 TB/s.

#define ALPHA_ 0.1f
constexpr int BATCH = 8192;
constexpr int NCLS  = 10000;
constexpr int FDIM  = 256;

typedef __attribute__((ext_vector_type(8))) short bf16x8;
typedef __attribute__((ext_vector_type(4))) float f32x4;

__device__ __forceinline__ unsigned short f2bf(float f) {
  unsigned int u = __float_as_uint(f);
  u += 0x7FFF + ((u >> 16) & 1);   // round-to-nearest-even
  return (unsigned short)(u >> 16);
}

// One wave per row: convert f32 row -> bf16 into ws, and compute sum(x*x).
__global__ void prep_kernel(const float* __restrict__ feat,
                            const float* __restrict__ centers,
                            unsigned short* __restrict__ fbf,
                            unsigned short* __restrict__ cbf,
                            float* __restrict__ fsq,
                            float* __restrict__ csq) {
  int gw = (int)((blockIdx.x * blockDim.x + threadIdx.x) >> 6);
  int lane = threadIdx.x & 63;
  if (gw >= BATCH + NCLS) return;
  const float* src; unsigned short* dst; float* sq;
  if (gw < BATCH) {
    src = feat + (size_t)gw * FDIM; dst = fbf + (size_t)gw * FDIM; sq = fsq + gw;
  } else {
    int r = gw - BATCH;
    src = centers + (size_t)r * FDIM; dst = cbf + (size_t)r * FDIM; sq = csq + r;
  }
  float4 v = reinterpret_cast<const float4*>(src)[lane];   // 64 lanes x 16B = 256 f32
  ushort4 b;
  b.x = f2bf(v.x); b.y = f2bf(v.y); b.z = f2bf(v.z); b.w = f2bf(v.w);
  reinterpret_cast<ushort4*>(dst)[lane] = b;
  float s = v.x*v.x + v.y*v.y + v.z*v.z + v.w*v.w;
  #pragma unroll
  for (int off = 32; off >= 1; off >>= 1) s += __shfl_xor(s, off, 64);
  if (lane == 0) *sq = s;
}

// 128x128 tile, BK=64, 4 waves (2x2), each wave 64x64 via 4x4 frags of 16x16x32.
#define BM 128
#define BN 128
#define BK 64
#define LDK 72   // +8 bf16 pad: row stride 144 B -> conflict-free b128 access

__global__ __launch_bounds__(256, 2)
void gemm_kernel(const unsigned short* __restrict__ fbf,
                 const unsigned short* __restrict__ cbf,
                 const float* __restrict__ fsq,
                 const float* __restrict__ csq,
                 const int* __restrict__ label,
                 float* __restrict__ out_logits,
                 float* __restrict__ out_margin) {
  __shared__ unsigned short As[BM * LDK];
  __shared__ unsigned short Bs[BN * LDK];

  const int NTN = (NCLS + BN - 1) / BN;  // 79
  const int NWG = (BATCH / BM) * NTN;    // 5056 (== 8 * 632)

  // XCD-bijective swizzle then GROUP_M=8 decomposition.
  int bid = blockIdx.x;
  int wg = (bid & 7) * (NWG >> 3) + (bid >> 3);
  int gsz = 8 * NTN;                     // 632
  int grp = wg / gsz;
  int rem = wg - grp * gsz;
  int mt = grp * 8 + (rem & 7);
  int nt = rem >> 3;

  const int tid  = threadIdx.x;
  const int lane = tid & 63;
  const int wid  = tid >> 6;
  const int wr   = (wid >> 1) * 64;
  const int wc   = (wid & 1) * 64;

  f32x4 acc[4][4];
  #pragma unroll
  for (int i = 0; i < 4; i++)
    #pragma unroll
    for (int j = 0; j < 4; j++) acc[i][j] = (f32x4){0.f, 0.f, 0.f, 0.f};

  const int srow = tid >> 3;          // 0..31
  const int scol = (tid & 7) * 8;     // 0..56, 8 bf16 = 16 B per load
  const size_t a_base = (size_t)(mt * BM) * FDIM;
  const int c0 = nt * BN;

  for (int kc = 0; kc < FDIM / BK; ++kc) {
    const int k0 = kc * BK;
    #pragma unroll
    for (int j = 0; j < 4; ++j) {
      int r = j * 32 + srow;
      bf16x8 v = *reinterpret_cast<const bf16x8*>(fbf + a_base + (size_t)r * FDIM + k0 + scol);
      *reinterpret_cast<bf16x8*>(&As[r * LDK + scol]) = v;
    }
    #pragma unroll
    for (int j = 0; j < 4; ++j) {
      int r = j * 32 + srow;
      int c = c0 + r;
      bf16x8 v = (bf16x8){0,0,0,0,0,0,0,0};
      if (c < NCLS) v = *reinterpret_cast<const bf16x8*>(cbf + (size_t)c * FDIM + k0 + scol);
      *reinterpret_cast<bf16x8*>(&Bs[r * LDK + scol]) = v;
    }
    __syncthreads();
    #pragma unroll
    for (int kk = 0; kk < BK / 32; ++kk) {
      const int kcol = kk * 32 + (lane >> 4) * 8;
      bf16x8 a[4], b[4];
      #pragma unroll
      for (int i = 0; i < 4; i++)
        a[i] = *reinterpret_cast<const bf16x8*>(&As[(wr + i * 16 + (lane & 15)) * LDK + kcol]);
      #pragma unroll
      for (int j = 0; j < 4; j++)
        b[j] = *reinterpret_cast<const bf16x8*>(&Bs[(wc + j * 16 + (lane & 15)) * LDK + kcol]);
      #pragma unroll
      for (int i = 0; i < 4; i++)
        #pragma unroll
        for (int j = 0; j < 4; j++)
          acc[i][j] = __builtin_amdgcn_mfma_f32_16x16x32_bf16(a[i], b[j], acc[i][j], 0, 0, 0);
    }
    __syncthreads();
  }

  // Epilogue: logits = cross - 0.5*(fsq+csq); margin = logits*(1+alpha) at label.
  #pragma unroll
  for (int i = 0; i < 4; i++) {
    int grow0 = mt * BM + wr + i * 16 + ((lane >> 4) << 2);
    float fs[4]; int lb[4];
    #pragma unroll
    for (int r = 0; r < 4; r++) { fs[r] = fsq[grow0 + r]; lb[r] = label[grow0 + r]; }
    #pragma unroll
    for (int j = 0; j < 4; j++) {
      int gcol = c0 + wc + j * 16 + (lane & 15);
      if (gcol >= NCLS) continue;
      float cs = csq[gcol];
      f32x4 v = acc[i][j];
      #pragma unroll
      for (int r = 0; r < 4; r++) {
        float logit = v[r] - 0.5f * (fs[r] + cs);
        size_t idx = (size_t)(grow0 + r) * NCLS + gcol;
        out_logits[idx] = logit;
        out_margin[idx] = (lb[r] == gcol) ? logit * (1.0f + ALPHA_) : logit;
      }
    }
  }
}

// likelihood = sum_b 0.5*||feat[b]-centers[label[b]]||^2 / B, deterministic 2-stage.
__global__ void lik_partial_kernel(const float* __restrict__ feat,
                                   const int* __restrict__ label,
                                   const float* __restrict__ centers,
                                   float* __restrict__ partial) {
  int t = threadIdx.x;          // 256 threads = one column each
  int b0 = blockIdx.x * 32;
  float acc = 0.f;
  for (int i = 0; i < 32; i++) {
    int row = b0 + i;
    int lb = label[row];
    float d = feat[(size_t)row * FDIM + t] - centers[(size_t)lb * FDIM + t];
    acc += d * d;
  }
  #pragma unroll
  for (int off = 32; off >= 1; off >>= 1) acc += __shfl_xor(acc, off, 64);
  __shared__ float red[4];
  if ((t & 63) == 0) red[t >> 6] = acc;
  __syncthreads();
  if (t == 0) partial[blockIdx.x] = red[0] + red[1] + red[2] + red[3];
}

__global__ void lik_final_kernel(const float* __restrict__ partial,
                                 float* __restrict__ out) {
  int t = threadIdx.x;  // 256
  float v = partial[t];
  #pragma unroll
  for (int off = 32; off >= 1; off >>= 1) v += __shfl_xor(v, off, 64);
  __shared__ float red[4];
  if ((t & 63) == 0) red[t >> 6] = v;
  __syncthreads();
  if (t == 0) out[0] = (red[0] + red[1] + red[2] + red[3]) * (1.0f / (2.0f * BATCH));
}

extern "C" void kernel_launch(void* const* d_in, const int* in_sizes, int n_in,
                              void* d_out, int out_size, void* d_ws, size_t ws_size,
                              hipStream_t stream) {
  const float* feat    = (const float*)d_in[0];
  const int*   label   = (const int*)d_in[1];
  const float* centers = (const float*)d_in[2];

  float* out        = (float*)d_out;
  float* out_logits = out;
  float* out_margin = out + (size_t)BATCH * NCLS;
  float* out_lik    = out + 2 * (size_t)BATCH * NCLS;

  char* ws = (char*)d_ws;
  unsigned short* fbf = (unsigned short*)ws;                                   // 4 MB
  unsigned short* cbf = (unsigned short*)(ws + (size_t)BATCH * FDIM * 2);      // 5 MB
  float* fsq     = (float*)(ws + (size_t)BATCH * FDIM * 2 + (size_t)NCLS * FDIM * 2);
  float* csq     = fsq + BATCH;
  float* partial = csq + NCLS;

  prep_kernel<<<(BATCH + NCLS) / 4, 256, 0, stream>>>(feat, centers, fbf, cbf, fsq, csq);
  lik_partial_kernel<<<BATCH / 32, 256, 0, stream>>>(feat, label, centers, partial);
  lik_final_kernel<<<1, 256, 0, stream>>>(partial, out_lik);
  gemm_kernel<<<(BATCH / BM) * ((NCLS + BN - 1) / BN), 256, 0, stream>>>(
      fbf, cbf, fsq, csq, label, out_logits, out_margin);
}

// Round 2
// 250.004 us; speedup vs baseline: 1.1213x; 1.1213x over previous
//
#include <hip/hip_runtime.h>
#include <hip/hip_bf16.h>

// LGM loss: logits/margin_logits [8192,10000] f32 + scalar likelihood.
// Write-bound: 655 MB of outputs -> ~100 us floor at 6.5 TB/s (fill-kernel calib).
// R2: swapped-operand MFMA (N-contiguous per lane -> float4 stores),
//     nt-fastest XCD block ordering (long HBM row runs), wider lik kernel.

#define ALPHA_ 0.1f
constexpr int BATCH = 8192;
constexpr int NCLS  = 10000;
constexpr int FDIM  = 256;

typedef __attribute__((ext_vector_type(8))) short bf16x8;
typedef __attribute__((ext_vector_type(4))) float f32x4;

__device__ __forceinline__ unsigned short f2bf(float f) {
  unsigned int u = __float_as_uint(f);
  u += 0x7FFF + ((u >> 16) & 1);   // round-to-nearest-even
  return (unsigned short)(u >> 16);
}

// One wave per row: convert f32 row -> bf16 into ws, and compute sum(x*x).
__global__ void prep_kernel(const float* __restrict__ feat,
                            const float* __restrict__ centers,
                            unsigned short* __restrict__ fbf,
                            unsigned short* __restrict__ cbf,
                            float* __restrict__ fsq,
                            float* __restrict__ csq) {
  int gw = (int)((blockIdx.x * blockDim.x + threadIdx.x) >> 6);
  int lane = threadIdx.x & 63;
  if (gw >= BATCH + NCLS) return;
  const float* src; unsigned short* dst; float* sq;
  if (gw < BATCH) {
    src = feat + (size_t)gw * FDIM; dst = fbf + (size_t)gw * FDIM; sq = fsq + gw;
  } else {
    int r = gw - BATCH;
    src = centers + (size_t)r * FDIM; dst = cbf + (size_t)r * FDIM; sq = csq + r;
  }
  float4 v = reinterpret_cast<const float4*>(src)[lane];   // 64 lanes x 16B = 256 f32
  ushort4 b;
  b.x = f2bf(v.x); b.y = f2bf(v.y); b.z = f2bf(v.z); b.w = f2bf(v.w);
  reinterpret_cast<ushort4*>(dst)[lane] = b;
  float s = v.x*v.x + v.y*v.y + v.z*v.z + v.w*v.w;
  #pragma unroll
  for (int off = 32; off >= 1; off >>= 1) s += __shfl_xor(s, off, 64);
  if (lane == 0) *sq = s;
}

// 128x128 tile, BK=64, 4 waves (2x2), each wave 64x64 via 4x4 frags of 16x16x32.
#define BM 128
#define BN 128
#define BK 64
#define LDK 72   // +8 bf16 pad: row stride 144 B -> uniform 8-lane/bank (b128 floor)

__global__ __launch_bounds__(256, 2)
void gemm_kernel(const unsigned short* __restrict__ fbf,
                 const unsigned short* __restrict__ cbf,
                 const float* __restrict__ fsq,
                 const float* __restrict__ csq,
                 const int* __restrict__ label,
                 float* __restrict__ out_logits,
                 float* __restrict__ out_margin) {
  __shared__ unsigned short As[BM * LDK];
  __shared__ unsigned short Bs[BN * LDK];

  const int NTN = (NCLS + BN - 1) / BN;  // 79
  const int NWG = (BATCH / BM) * NTN;    // 5056 == 8 * 632, 632 == 8*79

  // XCD-bijective split, then nt-fastest within each XCD chunk:
  // each XCD sweeps all 79 N-tiles of one M-band before moving to the next band.
  // -> co-resident blocks write long contiguous column runs of a 128-row band,
  //    and 79 consecutive blocks reuse one 64 KB A-panel from L2.
  int bid = blockIdx.x;
  int wg = (bid & 7) * (NWG >> 3) + (bid >> 3);
  int mt = wg / NTN;
  int nt = wg - mt * NTN;

  const int tid  = threadIdx.x;
  const int lane = tid & 63;
  const int wid  = tid >> 6;
  const int wr   = (wid >> 1) * 64;
  const int wc   = (wid & 1) * 64;

  f32x4 acc[4][4];
  #pragma unroll
  for (int i = 0; i < 4; i++)
    #pragma unroll
    for (int j = 0; j < 4; j++) acc[i][j] = (f32x4){0.f, 0.f, 0.f, 0.f};

  const int srow = tid >> 3;          // 0..31
  const int scol = (tid & 7) * 8;     // 0..56, 8 bf16 = 16 B per load
  const size_t a_base = (size_t)(mt * BM) * FDIM;
  const int c0 = nt * BN;

  for (int kc = 0; kc < FDIM / BK; ++kc) {
    const int k0 = kc * BK;
    #pragma unroll
    for (int j = 0; j < 4; ++j) {
      int r = j * 32 + srow;
      bf16x8 v = *reinterpret_cast<const bf16x8*>(fbf + a_base + (size_t)r * FDIM + k0 + scol);
      *reinterpret_cast<bf16x8*>(&As[r * LDK + scol]) = v;
    }
    #pragma unroll
    for (int j = 0; j < 4; ++j) {
      int r = j * 32 + srow;
      int c = c0 + r;
      bf16x8 v = (bf16x8){0,0,0,0,0,0,0,0};
      if (c < NCLS) v = *reinterpret_cast<const bf16x8*>(cbf + (size_t)c * FDIM + k0 + scol);
      *reinterpret_cast<bf16x8*>(&Bs[r * LDK + scol]) = v;
    }
    __syncthreads();
    #pragma unroll
    for (int kk = 0; kk < BK / 32; ++kk) {
      const int kcol = kk * 32 + (lane >> 4) * 8;
      bf16x8 a[4], b[4];
      #pragma unroll
      for (int i = 0; i < 4; i++)
        a[i] = *reinterpret_cast<const bf16x8*>(&As[(wr + i * 16 + (lane & 15)) * LDK + kcol]);
      #pragma unroll
      for (int j = 0; j < 4; j++)
        b[j] = *reinterpret_cast<const bf16x8*>(&Bs[(wc + j * 16 + (lane & 15)) * LDK + kcol]);
      // Swapped operands: D = mfma(B, A) stores C^T fragment -> per lane,
      // reg r = 4 consecutive N columns at a single M row -> float4 stores.
      #pragma unroll
      for (int i = 0; i < 4; i++)
        #pragma unroll
        for (int j = 0; j < 4; j++)
          acc[i][j] = __builtin_amdgcn_mfma_f32_16x16x32_bf16(b[j], a[i], acc[i][j], 0, 0, 0);
    }
    __syncthreads();
  }

  // Epilogue (swapped layout): m = lane&15 (+16*i), n = (lane>>4)*4 (+16*j), regs = n..n+3.
  const int mloc = wr + (lane & 15);
  const int nloc = wc + ((lane >> 4) << 2);
  #pragma unroll
  for (int i = 0; i < 4; i++) {
    int m = mt * BM + mloc + i * 16;
    float fs = fsq[m];
    int lb = label[m];
    size_t rowoff = (size_t)m * NCLS;
    #pragma unroll
    for (int j = 0; j < 4; j++) {
      int n0 = c0 + nloc + j * 16;
      if (n0 >= NCLS) continue;   // NCLS%4==0 and n0%4==0 -> float4 all-or-nothing
      float4 cs = *reinterpret_cast<const float4*>(&csq[n0]);
      f32x4 v = acc[i][j];
      float4 lg;
      lg.x = v[0] - 0.5f * (fs + cs.x);
      lg.y = v[1] - 0.5f * (fs + cs.y);
      lg.z = v[2] - 0.5f * (fs + cs.z);
      lg.w = v[3] - 0.5f * (fs + cs.w);
      *reinterpret_cast<float4*>(&out_logits[rowoff + n0]) = lg;
      float4 mg;
      mg.x = (lb == n0    ) ? lg.x * (1.0f + ALPHA_) : lg.x;
      mg.y = (lb == n0 + 1) ? lg.y * (1.0f + ALPHA_) : lg.y;
      mg.z = (lb == n0 + 2) ? lg.z * (1.0f + ALPHA_) : lg.z;
      mg.w = (lb == n0 + 3) ? lg.w * (1.0f + ALPHA_) : lg.w;
      *reinterpret_cast<float4*>(&out_margin[rowoff + n0]) = mg;
    }
  }
}

// likelihood = sum_b 0.5*||feat[b]-centers[label[b]]||^2 / B, deterministic 2-stage.
__global__ void lik_partial_kernel(const float* __restrict__ feat,
                                   const int* __restrict__ label,
                                   const float* __restrict__ centers,
                                   float* __restrict__ partial) {
  int t = threadIdx.x;          // 256 threads = one column each
  int b0 = blockIdx.x * 8;
  float acc = 0.f;
  #pragma unroll
  for (int i = 0; i < 8; i++) {
    int row = b0 + i;
    int lb = label[row];
    float d = feat[(size_t)row * FDIM + t] - centers[(size_t)lb * FDIM + t];
    acc += d * d;
  }
  #pragma unroll
  for (int off = 32; off >= 1; off >>= 1) acc += __shfl_xor(acc, off, 64);
  __shared__ float red[4];
  if ((t & 63) == 0) red[t >> 6] = acc;
  __syncthreads();
  if (t == 0) partial[blockIdx.x] = red[0] + red[1] + red[2] + red[3];
}

__global__ void lik_final_kernel(const float* __restrict__ partial,
                                 float* __restrict__ out) {
  int t = threadIdx.x;  // 256; 1024 partials
  float v = partial[t] + partial[t + 256] + partial[t + 512] + partial[t + 768];
  #pragma unroll
  for (int off = 32; off >= 1; off >>= 1) v += __shfl_xor(v, off, 64);
  __shared__ float red[4];
  if ((t & 63) == 0) red[t >> 6] = v;
  __syncthreads();
  if (t == 0) out[0] = (red[0] + red[1] + red[2] + red[3]) * (1.0f / (2.0f * BATCH));
}

extern "C" void kernel_launch(void* const* d_in, const int* in_sizes, int n_in,
                              void* d_out, int out_size, void* d_ws, size_t ws_size,
                              hipStream_t stream) {
  const float* feat    = (const float*)d_in[0];
  const int*   label   = (const int*)d_in[1];
  const float* centers = (const float*)d_in[2];

  float* out        = (float*)d_out;
  float* out_logits = out;
  float* out_margin = out + (size_t)BATCH * NCLS;
  float* out_lik    = out + 2 * (size_t)BATCH * NCLS;

  char* ws = (char*)d_ws;
  unsigned short* fbf = (unsigned short*)ws;                                   // 4 MB
  unsigned short* cbf = (unsigned short*)(ws + (size_t)BATCH * FDIM * 2);      // 5 MB
  float* fsq     = (float*)(ws + (size_t)BATCH * FDIM * 2 + (size_t)NCLS * FDIM * 2);
  float* csq     = fsq + BATCH;
  float* partial = csq + NCLS;

  prep_kernel<<<(BATCH + NCLS) / 4, 256, 0, stream>>>(feat, centers, fbf, cbf, fsq, csq);
  lik_partial_kernel<<<BATCH / 8, 256, 0, stream>>>(feat, label, centers, partial);
  lik_final_kernel<<<1, 256, 0, stream>>>(partial, out_lik);
  gemm_kernel<<<(BATCH / BM) * ((NCLS + BN - 1) / BN), 256, 0, stream>>>(
      fbf, cbf, fsq, csq, label, out_logits, out_margin);
}

// Round 3
// 248.143 us; speedup vs baseline: 1.1297x; 1.0075x over previous
//
#include <hip/hip_runtime.h>
#include <hip/hip_bf16.h>

// LGM loss: logits/margin_logits [8192,10000] f32 + scalar likelihood.
// Write-bound: 655 MB of outputs -> ~100 us floor at 6.7 TB/s (fill calib).
// R3: coalesced epilogue via LDS C-tile staging (512B runs/row) — R2's
//     direct fragment stores touched 64 distinct lines per wave-store.

#define ALPHA_ 0.1f
constexpr int BATCH = 8192;
constexpr int NCLS  = 10000;
constexpr int FDIM  = 256;

typedef __attribute__((ext_vector_type(8))) short bf16x8;
typedef __attribute__((ext_vector_type(4))) float f32x4;

__device__ __forceinline__ unsigned short f2bf(float f) {
  unsigned int u = __float_as_uint(f);
  u += 0x7FFF + ((u >> 16) & 1);   // round-to-nearest-even
  return (unsigned short)(u >> 16);
}

// One wave per row: convert f32 row -> bf16 into ws, and compute sum(x*x).
__global__ void prep_kernel(const float* __restrict__ feat,
                            const float* __restrict__ centers,
                            unsigned short* __restrict__ fbf,
                            unsigned short* __restrict__ cbf,
                            float* __restrict__ fsq,
                            float* __restrict__ csq) {
  int gw = (int)((blockIdx.x * blockDim.x + threadIdx.x) >> 6);
  int lane = threadIdx.x & 63;
  if (gw >= BATCH + NCLS) return;
  const float* src; unsigned short* dst; float* sq;
  if (gw < BATCH) {
    src = feat + (size_t)gw * FDIM; dst = fbf + (size_t)gw * FDIM; sq = fsq + gw;
  } else {
    int r = gw - BATCH;
    src = centers + (size_t)r * FDIM; dst = cbf + (size_t)r * FDIM; sq = csq + r;
  }
  float4 v = reinterpret_cast<const float4*>(src)[lane];   // 64 lanes x 16B = 256 f32
  ushort4 b;
  b.x = f2bf(v.x); b.y = f2bf(v.y); b.z = f2bf(v.z); b.w = f2bf(v.w);
  reinterpret_cast<ushort4*>(dst)[lane] = b;
  float s = v.x*v.x + v.y*v.y + v.z*v.z + v.w*v.w;
  #pragma unroll
  for (int off = 32; off >= 1; off >>= 1) s += __shfl_xor(s, off, 64);
  if (lane == 0) *sq = s;
}

// 128x128 tile, BK=64, 4 waves (2x2), each wave 64x64 via 4x4 frags of 16x16x32.
#define BM 128
#define BN 128
#define BK 64
#define LDK 72   // +8 bf16 pad: row stride 144 B -> conflict-free b128 LDS access

__global__ __launch_bounds__(256, 2)
void gemm_kernel(const unsigned short* __restrict__ fbf,
                 const unsigned short* __restrict__ cbf,
                 const float* __restrict__ fsq,
                 const float* __restrict__ csq,
                 const int* __restrict__ label,
                 float* __restrict__ out_logits,
                 float* __restrict__ out_margin) {
  // K-loop staging and epilogue C-staging share the same LDS (union):
  // As/Bs are dead after the final __syncthreads of the K-loop.
  __shared__ union {
    struct { unsigned short A[BM * LDK]; unsigned short B[BN * LDK]; } ab;
    float ct[64 * 128];   // one 64-row chunk of the C tile (32 KB)
  } sm;

  const int NTN = (NCLS + BN - 1) / BN;  // 79
  const int NWG = (BATCH / BM) * NTN;    // 5056 == 8 * 632

  // XCD-bijective split, nt-fastest within each XCD chunk (A-panel L2 reuse,
  // long column sweeps over a fixed 128-row band).
  int bid = blockIdx.x;
  int wg = (bid & 7) * (NWG >> 3) + (bid >> 3);
  int mt = wg / NTN;
  int nt = wg - mt * NTN;

  const int tid  = threadIdx.x;
  const int lane = tid & 63;
  const int wid  = tid >> 6;
  const int wr   = (wid >> 1) * 64;
  const int wc   = (wid & 1) * 64;

  f32x4 acc[4][4];
  #pragma unroll
  for (int i = 0; i < 4; i++)
    #pragma unroll
    for (int j = 0; j < 4; j++) acc[i][j] = (f32x4){0.f, 0.f, 0.f, 0.f};

  const int srow = tid >> 3;          // 0..31
  const int scol = (tid & 7) * 8;     // 0..56, 8 bf16 = 16 B per load
  const size_t a_base = (size_t)(mt * BM) * FDIM;
  const int c0 = nt * BN;

  for (int kc = 0; kc < FDIM / BK; ++kc) {
    const int k0 = kc * BK;
    #pragma unroll
    for (int j = 0; j < 4; ++j) {
      int r = j * 32 + srow;
      bf16x8 v = *reinterpret_cast<const bf16x8*>(fbf + a_base + (size_t)r * FDIM + k0 + scol);
      *reinterpret_cast<bf16x8*>(&sm.ab.A[r * LDK + scol]) = v;
    }
    #pragma unroll
    for (int j = 0; j < 4; ++j) {
      int r = j * 32 + srow;
      int c = c0 + r;
      bf16x8 v = (bf16x8){0,0,0,0,0,0,0,0};
      if (c < NCLS) v = *reinterpret_cast<const bf16x8*>(cbf + (size_t)c * FDIM + k0 + scol);
      *reinterpret_cast<bf16x8*>(&sm.ab.B[r * LDK + scol]) = v;
    }
    __syncthreads();
    #pragma unroll
    for (int kk = 0; kk < BK / 32; ++kk) {
      const int kcol = kk * 32 + (lane >> 4) * 8;
      bf16x8 a[4], b[4];
      #pragma unroll
      for (int i = 0; i < 4; i++)
        a[i] = *reinterpret_cast<const bf16x8*>(&sm.ab.A[(wr + i * 16 + (lane & 15)) * LDK + kcol]);
      #pragma unroll
      for (int j = 0; j < 4; j++)
        b[j] = *reinterpret_cast<const bf16x8*>(&sm.ab.B[(wc + j * 16 + (lane & 15)) * LDK + kcol]);
      // Swapped operands: per lane, reg r = 4 consecutive N columns at one M row.
      #pragma unroll
      for (int i = 0; i < 4; i++)
        #pragma unroll
        for (int j = 0; j < 4; j++)
          acc[i][j] = __builtin_amdgcn_mfma_f32_16x16x32_bf16(b[j], a[i], acc[i][j], 0, 0, 0);
    }
    __syncthreads();
  }

  // ---- Epilogue: two 64-row chunks staged through LDS, coalesced writeback ----
  // Fragment (i,j): M row = wr + i*16 + (lane&15), N chunk(4 cols) = wc/4 + 4j + (lane>>4).
  // LDS swizzle: physical chunk pc = c ^ (rr & 31), rr = row within chunk.
  const int mfrag = lane & 15;
  const int cfrag = (wc >> 2) + (lane >> 4);   // + 4j below
  #pragma unroll
  for (int ch = 0; ch < 2; ++ch) {
    if ((wid >> 1) == ch) {   // waves owning rows [ch*64, ch*64+64)
      #pragma unroll
      for (int i = 0; i < 4; i++) {
        int rr = i * 16 + mfrag;              // row within chunk, 0..63
        int m  = mt * BM + ch * 64 + rr;
        float fs = fsq[m];
        #pragma unroll
        for (int j = 0; j < 4; j++) {
          int c  = cfrag + 4 * j;             // logical 16B chunk, 0..31
          int n0 = c0 + 4 * c;
          int nc = (n0 <= NCLS - 4) ? n0 : (NCLS - 4);  // clamp csq read
          float4 cs = *reinterpret_cast<const float4*>(&csq[nc]);
          f32x4 v = acc[i][j];
          float4 lg;
          lg.x = v[0] - 0.5f * (fs + cs.x);
          lg.y = v[1] - 0.5f * (fs + cs.y);
          lg.z = v[2] - 0.5f * (fs + cs.z);
          lg.w = v[3] - 0.5f * (fs + cs.w);
          int pc = c ^ (rr & 31);
          *reinterpret_cast<float4*>(&sm.ct[rr * 128 + pc * 4]) = lg;
        }
      }
    }
    __syncthreads();
    // Readback: 8 rows/iter, 32 lanes/row -> 512B contiguous runs per row.
    #pragma unroll
    for (int it = 0; it < 8; ++it) {
      int rr = it * 8 + (tid >> 5);           // row within chunk
      int c  = tid & 31;
      int n0 = c0 + 4 * c;
      if (n0 >= NCLS) continue;               // NCLS%4==0 -> all-or-nothing
      int m  = mt * BM + ch * 64 + rr;
      int pc = c ^ (rr & 31);
      float4 lg = *reinterpret_cast<const float4*>(&sm.ct[rr * 128 + pc * 4]);
      size_t idx = (size_t)m * NCLS + n0;
      *reinterpret_cast<float4*>(&out_logits[idx]) = lg;
      int lb = label[m];
      float4 mg;
      mg.x = (lb == n0    ) ? lg.x * (1.0f + ALPHA_) : lg.x;
      mg.y = (lb == n0 + 1) ? lg.y * (1.0f + ALPHA_) : lg.y;
      mg.z = (lb == n0 + 2) ? lg.z * (1.0f + ALPHA_) : lg.z;
      mg.w = (lb == n0 + 3) ? lg.w * (1.0f + ALPHA_) : lg.w;
      *reinterpret_cast<float4*>(&out_margin[idx]) = mg;
    }
    __syncthreads();
  }
}

// likelihood = sum_b 0.5*||feat[b]-centers[label[b]]||^2 / B, deterministic 2-stage.
__global__ void lik_partial_kernel(const float* __restrict__ feat,
                                   const int* __restrict__ label,
                                   const float* __restrict__ centers,
                                   float* __restrict__ partial) {
  int t = threadIdx.x;          // 256 threads = one column each
  int b0 = blockIdx.x * 8;
  float acc = 0.f;
  #pragma unroll
  for (int i = 0; i < 8; i++) {
    int row = b0 + i;
    int lb = label[row];
    float d = feat[(size_t)row * FDIM + t] - centers[(size_t)lb * FDIM + t];
    acc += d * d;
  }
  #pragma unroll
  for (int off = 32; off >= 1; off >>= 1) acc += __shfl_xor(acc, off, 64);
  __shared__ float red[4];
  if ((t & 63) == 0) red[t >> 6] = acc;
  __syncthreads();
  if (t == 0) partial[blockIdx.x] = red[0] + red[1] + red[2] + red[3];
}

__global__ void lik_final_kernel(const float* __restrict__ partial,
                                 float* __restrict__ out) {
  int t = threadIdx.x;  // 256; 1024 partials
  float v = partial[t] + partial[t + 256] + partial[t + 512] + partial[t + 768];
  #pragma unroll
  for (int off = 32; off >= 1; off >>= 1) v += __shfl_xor(v, off, 64);
  __shared__ float red[4];
  if ((t & 63) == 0) red[t >> 6] = v;
  __syncthreads();
  if (t == 0) out[0] = (red[0] + red[1] + red[2] + red[3]) * (1.0f / (2.0f * BATCH));
}

extern "C" void kernel_launch(void* const* d_in, const int* in_sizes, int n_in,
                              void* d_out, int out_size, void* d_ws, size_t ws_size,
                              hipStream_t stream) {
  const float* feat    = (const float*)d_in[0];
  const int*   label   = (const int*)d_in[1];
  const float* centers = (const float*)d_in[2];

  float* out        = (float*)d_out;
  float* out_logits = out;
  float* out_margin = out + (size_t)BATCH * NCLS;
  float* out_lik    = out + 2 * (size_t)BATCH * NCLS;

  char* ws = (char*)d_ws;
  unsigned short* fbf = (unsigned short*)ws;                                   // 4 MB
  unsigned short* cbf = (unsigned short*)(ws + (size_t)BATCH * FDIM * 2);      // 5 MB
  float* fsq     = (float*)(ws + (size_t)BATCH * FDIM * 2 + (size_t)NCLS * FDIM * 2);
  float* csq     = fsq + BATCH;
  float* partial = csq + NCLS;

  prep_kernel<<<(BATCH + NCLS) / 4, 256, 0, stream>>>(feat, centers, fbf, cbf, fsq, csq);
  lik_partial_kernel<<<BATCH / 8, 256, 0, stream>>>(feat, label, centers, partial);
  lik_final_kernel<<<1, 256, 0, stream>>>(partial, out_lik);
  gemm_kernel<<<(BATCH / BM) * ((NCLS + BN - 1) / BN), 256, 0, stream>>>(
      fbf, cbf, fsq, csq, label, out_logits, out_margin);
}

// Round 4
// 220.875 us; speedup vs baseline: 1.2691x; 1.1235x over previous
//
#include <hip/hip_runtime.h>
#include <hip/hip_bf16.h>

// LGM loss: logits/margin_logits [8192,10000] f32 + scalar likelihood.
// R4: occupancy attack. R2->R3 (store coalescing) was NULL -> not transaction-
// bound. Theory: latency-bound at 2 waves/SIMD. Now 512-thread blocks,
// 8 waves, ~100 VGPR, 36.9KB LDS -> 4 blocks/CU = 32 waves/CU (4x).
// Nontemporal output stores keep B-panels resident in L2.

#define ALPHA_ 0.1f
constexpr int BATCH = 8192;
constexpr int NCLS  = 10000;
constexpr int FDIM  = 256;

typedef __attribute__((ext_vector_type(8))) short bf16x8;
typedef __attribute__((ext_vector_type(4))) float f32x4;

__device__ __forceinline__ unsigned short f2bf(float f) {
  unsigned int u = __float_as_uint(f);
  u += 0x7FFF + ((u >> 16) & 1);   // round-to-nearest-even
  return (unsigned short)(u >> 16);
}

// One wave per row: convert f32 row -> bf16 into ws, and compute sum(x*x).
__global__ void prep_kernel(const float* __restrict__ feat,
                            const float* __restrict__ centers,
                            unsigned short* __restrict__ fbf,
                            unsigned short* __restrict__ cbf,
                            float* __restrict__ fsq,
                            float* __restrict__ csq) {
  int gw = (int)((blockIdx.x * blockDim.x + threadIdx.x) >> 6);
  int lane = threadIdx.x & 63;
  if (gw >= BATCH + NCLS) return;
  const float* src; unsigned short* dst; float* sq;
  if (gw < BATCH) {
    src = feat + (size_t)gw * FDIM; dst = fbf + (size_t)gw * FDIM; sq = fsq + gw;
  } else {
    int r = gw - BATCH;
    src = centers + (size_t)r * FDIM; dst = cbf + (size_t)r * FDIM; sq = csq + r;
  }
  float4 v = reinterpret_cast<const float4*>(src)[lane];   // 64 lanes x 16B = 256 f32
  ushort4 b;
  b.x = f2bf(v.x); b.y = f2bf(v.y); b.z = f2bf(v.z); b.w = f2bf(v.w);
  reinterpret_cast<ushort4*>(dst)[lane] = b;
  float s = v.x*v.x + v.y*v.y + v.z*v.z + v.w*v.w;
  #pragma unroll
  for (int off = 32; off >= 1; off >>= 1) s += __shfl_xor(s, off, 64);
  if (lane == 0) *sq = s;
}

// 128x128 tile, BK=64, 8 waves (2Mx4N), each wave 64x32 via 4x2 frags of 16x16x32.
#define BM 128
#define BN 128
#define BK 64
#define LDK 72   // +8 bf16 pad: row stride 144 B -> conflict-free b128 LDS access

__global__ __launch_bounds__(512, 8)
void gemm_kernel(const unsigned short* __restrict__ fbf,
                 const unsigned short* __restrict__ cbf,
                 const float* __restrict__ fsq,
                 const float* __restrict__ csq,
                 const int* __restrict__ label,
                 float* __restrict__ out_logits,
                 float* __restrict__ out_margin) {
  __shared__ unsigned short As[BM * LDK];
  __shared__ unsigned short Bs[BN * LDK];

  const int NTN = (NCLS + BN - 1) / BN;  // 79
  const int NWG = (BATCH / BM) * NTN;    // 5056 == 8 * 632

  // XCD-bijective split, nt-fastest within each XCD chunk (A-panel L2 reuse,
  // concurrent blocks share one 128-row output band).
  int bid = blockIdx.x;
  int wg = (bid & 7) * (NWG >> 3) + (bid >> 3);
  int mt = wg / NTN;
  int nt = wg - mt * NTN;

  const int tid  = threadIdx.x;
  const int lane = tid & 63;
  const int wid  = tid >> 6;            // 0..7
  const int wr   = (wid >> 2) * 64;     // 2 waves in M
  const int wc   = (wid & 3) * 32;      // 4 waves in N

  f32x4 acc[4][2];
  #pragma unroll
  for (int i = 0; i < 4; i++)
    #pragma unroll
    for (int j = 0; j < 2; j++) acc[i][j] = (f32x4){0.f, 0.f, 0.f, 0.f};

  const int srow = tid >> 3;          // 0..63
  const int scol = (tid & 7) * 8;     // 0..56, 8 bf16 = 16 B per load
  const size_t a_base = (size_t)(mt * BM) * FDIM;
  const int c0 = nt * BN;

  for (int kc = 0; kc < FDIM / BK; ++kc) {
    const int k0 = kc * BK;
    #pragma unroll
    for (int j = 0; j < 2; ++j) {
      int r = j * 64 + srow;
      bf16x8 v = *reinterpret_cast<const bf16x8*>(fbf + a_base + (size_t)r * FDIM + k0 + scol);
      *reinterpret_cast<bf16x8*>(&As[r * LDK + scol]) = v;
    }
    #pragma unroll
    for (int j = 0; j < 2; ++j) {
      int r = j * 64 + srow;
      int c = c0 + r;
      bf16x8 v = (bf16x8){0,0,0,0,0,0,0,0};
      if (c < NCLS) v = *reinterpret_cast<const bf16x8*>(cbf + (size_t)c * FDIM + k0 + scol);
      *reinterpret_cast<bf16x8*>(&Bs[r * LDK + scol]) = v;
    }
    __syncthreads();
    #pragma unroll
    for (int kk = 0; kk < BK / 32; ++kk) {
      const int kcol = kk * 32 + (lane >> 4) * 8;
      bf16x8 a[4], b[2];
      #pragma unroll
      for (int i = 0; i < 4; i++)
        a[i] = *reinterpret_cast<const bf16x8*>(&As[(wr + i * 16 + (lane & 15)) * LDK + kcol]);
      #pragma unroll
      for (int j = 0; j < 2; j++)
        b[j] = *reinterpret_cast<const bf16x8*>(&Bs[(wc + j * 16 + (lane & 15)) * LDK + kcol]);
      // Swapped operands: per lane, reg r = 4 consecutive N columns at one M row.
      #pragma unroll
      for (int i = 0; i < 4; i++)
        #pragma unroll
        for (int j = 0; j < 2; j++)
          acc[i][j] = __builtin_amdgcn_mfma_f32_16x16x32_bf16(b[j], a[i], acc[i][j], 0, 0, 0);
    }
    __syncthreads();
  }

  // Epilogue (swapped layout): m = wr + i*16 + (lane&15), n = wc + j*16 + (lane>>4)*4.
  const int mloc = wr + (lane & 15);
  const int nbase = wc + ((lane >> 4) << 2);
  #pragma unroll
  for (int i = 0; i < 4; i++) {
    int m = mt * BM + mloc + i * 16;
    float fs = fsq[m];
    int lb = label[m];
    size_t rowoff = (size_t)m * NCLS;
    #pragma unroll
    for (int j = 0; j < 2; j++) {
      int n0 = c0 + nbase + j * 16;
      if (n0 >= NCLS) continue;   // NCLS%4==0 and n0%4==0 -> float4 all-or-nothing
      float4 cs = *reinterpret_cast<const float4*>(&csq[n0]);
      f32x4 v = acc[i][j];
      f32x4 lg;
      lg[0] = v[0] - 0.5f * (fs + cs.x);
      lg[1] = v[1] - 0.5f * (fs + cs.y);
      lg[2] = v[2] - 0.5f * (fs + cs.z);
      lg[3] = v[3] - 0.5f * (fs + cs.w);
      __builtin_nontemporal_store(lg, reinterpret_cast<f32x4*>(&out_logits[rowoff + n0]));
      f32x4 mg;
      mg[0] = (lb == n0    ) ? lg[0] * (1.0f + ALPHA_) : lg[0];
      mg[1] = (lb == n0 + 1) ? lg[1] * (1.0f + ALPHA_) : lg[1];
      mg[2] = (lb == n0 + 2) ? lg[2] * (1.0f + ALPHA_) : lg[2];
      mg[3] = (lb == n0 + 3) ? lg[3] * (1.0f + ALPHA_) : lg[3];
      __builtin_nontemporal_store(mg, reinterpret_cast<f32x4*>(&out_margin[rowoff + n0]));
    }
  }
}

// likelihood = sum_b 0.5*||feat[b]-centers[label[b]]||^2 / B, deterministic 2-stage.
__global__ void lik_partial_kernel(const float* __restrict__ feat,
                                   const int* __restrict__ label,
                                   const float* __restrict__ centers,
                                   float* __restrict__ partial) {
  int t = threadIdx.x;          // 256 threads = one column each
  int b0 = blockIdx.x * 8;
  float acc = 0.f;
  #pragma unroll
  for (int i = 0; i < 8; i++) {
    int row = b0 + i;
    int lb = label[row];
    float d = feat[(size_t)row * FDIM + t] - centers[(size_t)lb * FDIM + t];
    acc += d * d;
  }
  #pragma unroll
  for (int off = 32; off >= 1; off >>= 1) acc += __shfl_xor(acc, off, 64);
  __shared__ float red[4];
  if ((t & 63) == 0) red[t >> 6] = acc;
  __syncthreads();
  if (t == 0) partial[blockIdx.x] = red[0] + red[1] + red[2] + red[3];
}

__global__ void lik_final_kernel(const float* __restrict__ partial,
                                 float* __restrict__ out) {
  int t = threadIdx.x;  // 256; 1024 partials
  float v = partial[t] + partial[t + 256] + partial[t + 512] + partial[t + 768];
  #pragma unroll
  for (int off = 32; off >= 1; off >>= 1) v += __shfl_xor(v, off, 64);
  __shared__ float red[4];
  if ((t & 63) == 0) red[t >> 6] = v;
  __syncthreads();
  if (t == 0) out[0] = (red[0] + red[1] + red[2] + red[3]) * (1.0f / (2.0f * BATCH));
}

extern "C" void kernel_launch(void* const* d_in, const int* in_sizes, int n_in,
                              void* d_out, int out_size, void* d_ws, size_t ws_size,
                              hipStream_t stream) {
  const float* feat    = (const float*)d_in[0];
  const int*   label   = (const int*)d_in[1];
  const float* centers = (const float*)d_in[2];

  float* out        = (float*)d_out;
  float* out_logits = out;
  float* out_margin = out + (size_t)BATCH * NCLS;
  float* out_lik    = out + 2 * (size_t)BATCH * NCLS;

  char* ws = (char*)d_ws;
  unsigned short* fbf = (unsigned short*)ws;                                   // 4 MB
  unsigned short* cbf = (unsigned short*)(ws + (size_t)BATCH * FDIM * 2);      // 5 MB
  float* fsq     = (float*)(ws + (size_t)BATCH * FDIM * 2 + (size_t)NCLS * FDIM * 2);
  float* csq     = fsq + BATCH;
  float* partial = csq + NCLS;

  prep_kernel<<<(BATCH + NCLS) / 4, 256, 0, stream>>>(feat, centers, fbf, cbf, fsq, csq);
  lik_partial_kernel<<<BATCH / 8, 256, 0, stream>>>(feat, label, centers, partial);
  lik_final_kernel<<<1, 256, 0, stream>>>(partial, out_lik);
  gemm_kernel<<<(BATCH / BM) * ((NCLS + BN - 1) / BN), 512, 0, stream>>>(
      fbf, cbf, fsq, csq, label, out_logits, out_margin);
}

// Round 5
// 210.717 us; speedup vs baseline: 1.3303x; 1.0482x over previous
//
#include <hip/hip_runtime.h>
#include <hip/hip_bf16.h>

// LGM loss: logits/margin_logits [8192,10000] f32 + scalar likelihood.
// R5: pipelined K-loop. R2/R3 store-shape changes were NULL; R4 occupancy
// gave -27us. Serial budget says phases don't overlap (MFMA 21 + LDS 51 +
// writes 100 ~= observed 195us gemm). Fix: register-staged double-buffered
// LDS (issue loads for t+1 before computing t, ds_write after), ONE barrier
// per K-step, XOR-swizzled LDS (2-way max on frag reads), honest
// __launch_bounds__(512,4) -> 2 blocks/CU, 16 waves/CU, no spills.

#define ALPHA_ 0.1f
constexpr int BATCH = 8192;
constexpr int NCLS  = 10000;
constexpr int FDIM  = 256;

typedef __attribute__((ext_vector_type(8))) short bf16x8;
typedef __attribute__((ext_vector_type(4))) float f32x4;

__device__ __forceinline__ unsigned short f2bf(float f) {
  unsigned int u = __float_as_uint(f);
  u += 0x7FFF + ((u >> 16) & 1);   // round-to-nearest-even
  return (unsigned short)(u >> 16);
}

// One wave per row: convert f32 row -> bf16 into ws, and compute sum(x*x).
__global__ void prep_kernel(const float* __restrict__ feat,
                            const float* __restrict__ centers,
                            unsigned short* __restrict__ fbf,
                            unsigned short* __restrict__ cbf,
                            float* __restrict__ fsq,
                            float* __restrict__ csq) {
  int gw = (int)((blockIdx.x * blockDim.x + threadIdx.x) >> 6);
  int lane = threadIdx.x & 63;
  if (gw >= BATCH + NCLS) return;
  const float* src; unsigned short* dst; float* sq;
  if (gw < BATCH) {
    src = feat + (size_t)gw * FDIM; dst = fbf + (size_t)gw * FDIM; sq = fsq + gw;
  } else {
    int r = gw - BATCH;
    src = centers + (size_t)r * FDIM; dst = cbf + (size_t)r * FDIM; sq = csq + r;
  }
  float4 v = reinterpret_cast<const float4*>(src)[lane];   // 64 lanes x 16B = 256 f32
  ushort4 b;
  b.x = f2bf(v.x); b.y = f2bf(v.y); b.z = f2bf(v.z); b.w = f2bf(v.w);
  reinterpret_cast<ushort4*>(dst)[lane] = b;
  float s = v.x*v.x + v.y*v.y + v.z*v.z + v.w*v.w;
  #pragma unroll
  for (int off = 32; off >= 1; off >>= 1) s += __shfl_xor(s, off, 64);
  if (lane == 0) *sq = s;
}

// 128x128 tile, BK=64, 8 waves (2Mx4N), each wave 64x32 via 4x2 frags of 16x16x32.
#define BM 128
#define BN 128
#define BK 64

__global__ __launch_bounds__(512, 4)
void gemm_kernel(const unsigned short* __restrict__ fbf,
                 const unsigned short* __restrict__ cbf,
                 const float* __restrict__ fsq,
                 const float* __restrict__ csq,
                 const int* __restrict__ label,
                 float* __restrict__ out_logits,
                 float* __restrict__ out_margin) {
  // Double-buffered, XOR-swizzled (slot = chunk ^ (row&7), 16B chunks).
  __shared__ unsigned short As[2][BM * BK];   // 16 KB each
  __shared__ unsigned short Bs[2][BN * BK];   // 16 KB each

  const int NTN = (NCLS + BN - 1) / BN;  // 79
  const int NWG = (BATCH / BM) * NTN;    // 5056 == 8 * 632

  // XCD-bijective split, nt-fastest within each XCD chunk.
  int bid = blockIdx.x;
  int wg = (bid & 7) * (NWG >> 3) + (bid >> 3);
  int mt = wg / NTN;
  int nt = wg - mt * NTN;

  const int tid  = threadIdx.x;
  const int lane = tid & 63;
  const int wid  = tid >> 6;            // 0..7
  const int wr   = (wid >> 2) * 64;     // 2 waves in M
  const int wc   = (wid & 3) * 32;      // 4 waves in N

  f32x4 acc[4][2];
  #pragma unroll
  for (int i = 0; i < 4; i++)
    #pragma unroll
    for (int j = 0; j < 2; j++) acc[i][j] = (f32x4){0.f, 0.f, 0.f, 0.f};

  // Staging mapping: thread -> (row sr+64j, 16B chunk sc) of the 128x64 tile.
  const int sr = tid >> 3;          // 0..63
  const int sc = tid & 7;           // chunk 0..7 (8 bf16 each)
  const size_t a_base = (size_t)(mt * BM) * FDIM;
  const int c0 = nt * BN;

  bf16x8 va[2], vb[2];
  // ---- load tile kc into staging regs (issued early; consumed by STORE) ----
  #define LOADT(kc_) do {                                                      \
    int k0 = (kc_) * BK;                                                       \
    _Pragma("unroll")                                                          \
    for (int j = 0; j < 2; ++j) {                                              \
      int r = j * 64 + sr;                                                     \
      va[j] = *reinterpret_cast<const bf16x8*>(fbf + a_base + (size_t)r * FDIM + k0 + sc * 8); \
      int cc = c0 + r; cc = (cc < NCLS) ? cc : (NCLS - 1);                     \
      vb[j] = *reinterpret_cast<const bf16x8*>(cbf + (size_t)cc * FDIM + k0 + sc * 8); \
    }                                                                          \
  } while (0)
  // ---- write staging regs into LDS buffer b_ (XOR swizzle) ----
  #define STORET(b_) do {                                                      \
    _Pragma("unroll")                                                          \
    for (int j = 0; j < 2; ++j) {                                              \
      int r = j * 64 + sr;                                                     \
      int off = r * BK + ((sc ^ (r & 7)) * 8);                                 \
      *reinterpret_cast<bf16x8*>(&As[b_][off]) = va[j];                        \
      *reinterpret_cast<bf16x8*>(&Bs[b_][off]) = vb[j];                        \
    }                                                                          \
  } while (0)

  LOADT(0);
  STORET(0);

  #pragma unroll
  for (int kc = 0; kc < FDIM / BK; ++kc) {
    const int cur = kc & 1;
    if (kc < FDIM / BK - 1) LOADT(kc + 1);   // issue next tile's loads now
    __syncthreads();                          // buf[cur] writes visible
    #pragma unroll
    for (int kk = 0; kk < BK / 32; ++kk) {
      const int ch = kk * 4 + (lane >> 4);    // 16B chunk within row
      bf16x8 a[4], b[2];
      #pragma unroll
      for (int i = 0; i < 4; i++) {
        int row = wr + i * 16 + (lane & 15);
        a[i] = *reinterpret_cast<const bf16x8*>(&As[cur][row * BK + ((ch ^ (row & 7)) * 8)]);
      }
      #pragma unroll
      for (int j = 0; j < 2; j++) {
        int row = wc + j * 16 + (lane & 15);
        b[j] = *reinterpret_cast<const bf16x8*>(&Bs[cur][row * BK + ((ch ^ (row & 7)) * 8)]);
      }
      // Swapped operands: per lane, reg r = 4 consecutive N columns at one M row.
      #pragma unroll
      for (int i = 0; i < 4; i++)
        #pragma unroll
        for (int j = 0; j < 2; j++)
          acc[i][j] = __builtin_amdgcn_mfma_f32_16x16x32_bf16(b[j], a[i], acc[i][j], 0, 0, 0);
    }
    if (kc < FDIM / BK - 1) STORET(cur ^ 1);  // fill other buffer (readers of it
                                              // finished before last barrier)
  }

  // Epilogue (swapped layout): m = wr + i*16 + (lane&15), n = wc + j*16 + (lane>>4)*4.
  const int mloc = wr + (lane & 15);
  const int nbase = wc + ((lane >> 4) << 2);
  #pragma unroll
  for (int i = 0; i < 4; i++) {
    int m = mt * BM + mloc + i * 16;
    float fs = fsq[m];
    int lb = label[m];
    size_t rowoff = (size_t)m * NCLS;
    #pragma unroll
    for (int j = 0; j < 2; j++) {
      int n0 = c0 + nbase + j * 16;
      if (n0 >= NCLS) continue;   // NCLS%4==0 and n0%4==0 -> float4 all-or-nothing
      float4 cs = *reinterpret_cast<const float4*>(&csq[n0]);
      f32x4 v = acc[i][j];
      f32x4 lg;
      lg[0] = v[0] - 0.5f * (fs + cs.x);
      lg[1] = v[1] - 0.5f * (fs + cs.y);
      lg[2] = v[2] - 0.5f * (fs + cs.z);
      lg[3] = v[3] - 0.5f * (fs + cs.w);
      __builtin_nontemporal_store(lg, reinterpret_cast<f32x4*>(&out_logits[rowoff + n0]));
      f32x4 mg;
      mg[0] = (lb == n0    ) ? lg[0] * (1.0f + ALPHA_) : lg[0];
      mg[1] = (lb == n0 + 1) ? lg[1] * (1.0f + ALPHA_) : lg[1];
      mg[2] = (lb == n0 + 2) ? lg[2] * (1.0f + ALPHA_) : lg[2];
      mg[3] = (lb == n0 + 3) ? lg[3] * (1.0f + ALPHA_) : lg[3];
      __builtin_nontemporal_store(mg, reinterpret_cast<f32x4*>(&out_margin[rowoff + n0]));
    }
  }
  #undef LOADT
  #undef STORET
}

// likelihood = sum_b 0.5*||feat[b]-centers[label[b]]||^2 / B, deterministic 2-stage.
__global__ void lik_partial_kernel(const float* __restrict__ feat,
                                   const int* __restrict__ label,
                                   const float* __restrict__ centers,
                                   float* __restrict__ partial) {
  int t = threadIdx.x;          // 256 threads = one column each
  int b0 = blockIdx.x * 8;
  float acc = 0.f;
  #pragma unroll
  for (int i = 0; i < 8; i++) {
    int row = b0 + i;
    int lb = label[row];
    float d = feat[(size_t)row * FDIM + t] - centers[(size_t)lb * FDIM + t];
    acc += d * d;
  }
  #pragma unroll
  for (int off = 32; off >= 1; off >>= 1) acc += __shfl_xor(acc, off, 64);
  __shared__ float red[4];
  if ((t & 63) == 0) red[t >> 6] = acc;
  __syncthreads();
  if (t == 0) partial[blockIdx.x] = red[0] + red[1] + red[2] + red[3];
}

__global__ void lik_final_kernel(const float* __restrict__ partial,
                                 float* __restrict__ out) {
  int t = threadIdx.x;  // 256; 1024 partials
  float v = partial[t] + partial[t + 256] + partial[t + 512] + partial[t + 768];
  #pragma unroll
  for (int off = 32; off >= 1; off >>= 1) v += __shfl_xor(v, off, 64);
  __shared__ float red[4];
  if ((t & 63) == 0) red[t >> 6] = v;
  __syncthreads();
  if (t == 0) out[0] = (red[0] + red[1] + red[2] + red[3]) * (1.0f / (2.0f * BATCH));
}

extern "C" void kernel_launch(void* const* d_in, const int* in_sizes, int n_in,
                              void* d_out, int out_size, void* d_ws, size_t ws_size,
                              hipStream_t stream) {
  const float* feat    = (const float*)d_in[0];
  const int*   label   = (const int*)d_in[1];
  const float* centers = (const float*)d_in[2];

  float* out        = (float*)d_out;
  float* out_logits = out;
  float* out_margin = out + (size_t)BATCH * NCLS;
  float* out_lik    = out + 2 * (size_t)BATCH * NCLS;

  char* ws = (char*)d_ws;
  unsigned short* fbf = (unsigned short*)ws;                                   // 4 MB
  unsigned short* cbf = (unsigned short*)(ws + (size_t)BATCH * FDIM * 2);      // 5 MB
  float* fsq     = (float*)(ws + (size_t)BATCH * FDIM * 2 + (size_t)NCLS * FDIM * 2);
  float* csq     = fsq + BATCH;
  float* partial = csq + NCLS;

  prep_kernel<<<(BATCH + NCLS) / 4, 256, 0, stream>>>(feat, centers, fbf, cbf, fsq, csq);
  lik_partial_kernel<<<BATCH / 8, 256, 0, stream>>>(feat, label, centers, partial);
  lik_final_kernel<<<1, 256, 0, stream>>>(partial, out_lik);
  gemm_kernel<<<(BATCH / BM) * ((NCLS + BN - 1) / BN), 512, 0, stream>>>(
      fbf, cbf, fsq, csq, label, out_logits, out_margin);
}

// Round 6
// 200.156 us; speedup vs baseline: 1.4005x; 1.0528x over previous
//
#include <hip/hip_runtime.h>
#include <hip/hip_bf16.h>

// LGM loss: logits/margin_logits [8192,10000] f32 + scalar likelihood.
// R6: (a) DROP nontemporal stores — theory: nt=evict-first turns our two
// half-line (64B) store instrs per 128B output line into partial-line DRAM
// writes (2x write cost). Normal stores merge in writeback L2. NT was never
// isolated (bundled with R4's occupancy fix).
// (b) Fold likelihood into GEMM epilogue: lik = (1/B) sum_b(-logits[b,label_b]);
// exactly one thread computes each -> lik_row[8192] + 2us reduce. Removes the
// lik_partial gather pass (~12us of serial small-kernel time).
// R5 pipeline kept: reg-staged dbuf LDS, XOR swizzle, 1 barrier/kc, 512thr.

#define ALPHA_ 0.1f
constexpr int BATCH = 8192;
constexpr int NCLS  = 10000;
constexpr int FDIM  = 256;

typedef __attribute__((ext_vector_type(8))) short bf16x8;
typedef __attribute__((ext_vector_type(4))) float f32x4;

__device__ __forceinline__ unsigned short f2bf(float f) {
  unsigned int u = __float_as_uint(f);
  u += 0x7FFF + ((u >> 16) & 1);   // round-to-nearest-even
  return (unsigned short)(u >> 16);
}

// One wave per row: convert f32 row -> bf16 into ws, and compute sum(x*x).
__global__ void prep_kernel(const float* __restrict__ feat,
                            const float* __restrict__ centers,
                            unsigned short* __restrict__ fbf,
                            unsigned short* __restrict__ cbf,
                            float* __restrict__ fsq,
                            float* __restrict__ csq) {
  int gw = (int)((blockIdx.x * blockDim.x + threadIdx.x) >> 6);
  int lane = threadIdx.x & 63;
  if (gw >= BATCH + NCLS) return;
  const float* src; unsigned short* dst; float* sq;
  if (gw < BATCH) {
    src = feat + (size_t)gw * FDIM; dst = fbf + (size_t)gw * FDIM; sq = fsq + gw;
  } else {
    int r = gw - BATCH;
    src = centers + (size_t)r * FDIM; dst = cbf + (size_t)r * FDIM; sq = csq + r;
  }
  float4 v = reinterpret_cast<const float4*>(src)[lane];   // 64 lanes x 16B = 256 f32
  ushort4 b;
  b.x = f2bf(v.x); b.y = f2bf(v.y); b.z = f2bf(v.z); b.w = f2bf(v.w);
  reinterpret_cast<ushort4*>(dst)[lane] = b;
  float s = v.x*v.x + v.y*v.y + v.z*v.z + v.w*v.w;
  #pragma unroll
  for (int off = 32; off >= 1; off >>= 1) s += __shfl_xor(s, off, 64);
  if (lane == 0) *sq = s;
}

// 128x128 tile, BK=64, 8 waves (2Mx4N), each wave 64x32 via 4x2 frags of 16x16x32.
#define BM 128
#define BN 128
#define BK 64

__global__ __launch_bounds__(512, 4)
void gemm_kernel(const unsigned short* __restrict__ fbf,
                 const unsigned short* __restrict__ cbf,
                 const float* __restrict__ fsq,
                 const float* __restrict__ csq,
                 const int* __restrict__ label,
                 float* __restrict__ out_logits,
                 float* __restrict__ out_margin,
                 float* __restrict__ lik_row) {
  // Double-buffered, XOR-swizzled (slot = chunk ^ (row&7), 16B chunks).
  __shared__ unsigned short As[2][BM * BK];   // 16 KB each
  __shared__ unsigned short Bs[2][BN * BK];   // 16 KB each

  const int NTN = (NCLS + BN - 1) / BN;  // 79
  const int NWG = (BATCH / BM) * NTN;    // 5056 == 8 * 632

  // XCD-bijective split, nt-fastest within each XCD chunk.
  int bid = blockIdx.x;
  int wg = (bid & 7) * (NWG >> 3) + (bid >> 3);
  int mt = wg / NTN;
  int nt = wg - mt * NTN;

  const int tid  = threadIdx.x;
  const int lane = tid & 63;
  const int wid  = tid >> 6;            // 0..7
  const int wr   = (wid >> 2) * 64;     // 2 waves in M
  const int wc   = (wid & 3) * 32;      // 4 waves in N

  f32x4 acc[4][2];
  #pragma unroll
  for (int i = 0; i < 4; i++)
    #pragma unroll
    for (int j = 0; j < 2; j++) acc[i][j] = (f32x4){0.f, 0.f, 0.f, 0.f};

  // Staging mapping: thread -> (row sr+64j, 16B chunk sc) of the 128x64 tile.
  const int sr = tid >> 3;          // 0..63
  const int sc = tid & 7;           // chunk 0..7 (8 bf16 each)
  const size_t a_base = (size_t)(mt * BM) * FDIM;
  const int c0 = nt * BN;

  bf16x8 va[2], vb[2];
  // ---- load tile kc into staging regs (issued early; consumed by STORE) ----
  #define LOADT(kc_) do {                                                      \
    int k0 = (kc_) * BK;                                                       \
    _Pragma("unroll")                                                          \
    for (int j = 0; j < 2; ++j) {                                              \
      int r = j * 64 + sr;                                                     \
      va[j] = *reinterpret_cast<const bf16x8*>(fbf + a_base + (size_t)r * FDIM + k0 + sc * 8); \
      int cc = c0 + r; cc = (cc < NCLS) ? cc : (NCLS - 1);                     \
      vb[j] = *reinterpret_cast<const bf16x8*>(cbf + (size_t)cc * FDIM + k0 + sc * 8); \
    }                                                                          \
  } while (0)
  // ---- write staging regs into LDS buffer b_ (XOR swizzle) ----
  #define STORET(b_) do {                                                      \
    _Pragma("unroll")                                                          \
    for (int j = 0; j < 2; ++j) {                                              \
      int r = j * 64 + sr;                                                     \
      int off = r * BK + ((sc ^ (r & 7)) * 8);                                 \
      *reinterpret_cast<bf16x8*>(&As[b_][off]) = va[j];                        \
      *reinterpret_cast<bf16x8*>(&Bs[b_][off]) = vb[j];                        \
    }                                                                          \
  } while (0)

  LOADT(0);
  STORET(0);

  #pragma unroll
  for (int kc = 0; kc < FDIM / BK; ++kc) {
    const int cur = kc & 1;
    if (kc < FDIM / BK - 1) LOADT(kc + 1);   // issue next tile's loads now
    __syncthreads();                          // buf[cur] writes visible
    #pragma unroll
    for (int kk = 0; kk < BK / 32; ++kk) {
      const int ch = kk * 4 + (lane >> 4);    // 16B chunk within row
      bf16x8 a[4], b[2];
      #pragma unroll
      for (int i = 0; i < 4; i++) {
        int row = wr + i * 16 + (lane & 15);
        a[i] = *reinterpret_cast<const bf16x8*>(&As[cur][row * BK + ((ch ^ (row & 7)) * 8)]);
      }
      #pragma unroll
      for (int j = 0; j < 2; j++) {
        int row = wc + j * 16 + (lane & 15);
        b[j] = *reinterpret_cast<const bf16x8*>(&Bs[cur][row * BK + ((ch ^ (row & 7)) * 8)]);
      }
      // Swapped operands: per lane, reg r = 4 consecutive N columns at one M row.
      #pragma unroll
      for (int i = 0; i < 4; i++)
        #pragma unroll
        for (int j = 0; j < 2; j++)
          acc[i][j] = __builtin_amdgcn_mfma_f32_16x16x32_bf16(b[j], a[i], acc[i][j], 0, 0, 0);
    }
    if (kc < FDIM / BK - 1) STORET(cur ^ 1);  // fill other buffer
  }

  // Epilogue (swapped layout): m = wr + i*16 + (lane&15), n = wc + j*16 + (lane>>4)*4.
  // Plain (cached) stores: both 64B halves of each 128B line merge in L2.
  const int mloc = wr + (lane & 15);
  const int nbase = wc + ((lane >> 4) << 2);
  #pragma unroll
  for (int i = 0; i < 4; i++) {
    int m = mt * BM + mloc + i * 16;
    float fs = fsq[m];
    int lb = label[m];
    size_t rowoff = (size_t)m * NCLS;
    #pragma unroll
    for (int j = 0; j < 2; j++) {
      int n0 = c0 + nbase + j * 16;
      if (n0 >= NCLS) continue;   // NCLS%4==0 and n0%4==0 -> float4 all-or-nothing
      float4 cs = *reinterpret_cast<const float4*>(&csq[n0]);
      f32x4 v = acc[i][j];
      f32x4 lg;
      lg[0] = v[0] - 0.5f * (fs + cs.x);
      lg[1] = v[1] - 0.5f * (fs + cs.y);
      lg[2] = v[2] - 0.5f * (fs + cs.z);
      lg[3] = v[3] - 0.5f * (fs + cs.w);
      *reinterpret_cast<f32x4*>(&out_logits[rowoff + n0]) = lg;
      f32x4 mg;
      mg[0] = (lb == n0    ) ? lg[0] * (1.0f + ALPHA_) : lg[0];
      mg[1] = (lb == n0 + 1) ? lg[1] * (1.0f + ALPHA_) : lg[1];
      mg[2] = (lb == n0 + 2) ? lg[2] * (1.0f + ALPHA_) : lg[2];
      mg[3] = (lb == n0 + 3) ? lg[3] * (1.0f + ALPHA_) : lg[3];
      *reinterpret_cast<f32x4*>(&out_margin[rowoff + n0]) = mg;
      // Likelihood fold: exactly one (block,thread) in the grid hits each row's
      // label column -> single deterministic writer per lik_row[m].
      if (lb == n0)          lik_row[m] = -lg[0];
      else if (lb == n0 + 1) lik_row[m] = -lg[1];
      else if (lb == n0 + 2) lik_row[m] = -lg[2];
      else if (lb == n0 + 3) lik_row[m] = -lg[3];
    }
  }
  #undef LOADT
  #undef STORET
}

// likelihood = (1/B) * sum_m lik_row[m]; 1024 threads, deterministic tree.
__global__ void lik_reduce_kernel(const float* __restrict__ lik_row,
                                  float* __restrict__ out) {
  int t = threadIdx.x;  // 1024
  float v = 0.f;
  #pragma unroll
  for (int i = 0; i < BATCH / 1024; i++) v += lik_row[t + i * 1024];
  #pragma unroll
  for (int off = 32; off >= 1; off >>= 1) v += __shfl_xor(v, off, 64);
  __shared__ float red[16];
  if ((t & 63) == 0) red[t >> 6] = v;
  __syncthreads();
  if (t == 0) {
    float s = 0.f;
    #pragma unroll
    for (int i = 0; i < 16; i++) s += red[i];
    out[0] = s * (1.0f / BATCH);
  }
}

extern "C" void kernel_launch(void* const* d_in, const int* in_sizes, int n_in,
                              void* d_out, int out_size, void* d_ws, size_t ws_size,
                              hipStream_t stream) {
  const float* feat    = (const float*)d_in[0];
  const int*   label   = (const int*)d_in[1];
  const float* centers = (const float*)d_in[2];

  float* out        = (float*)d_out;
  float* out_logits = out;
  float* out_margin = out + (size_t)BATCH * NCLS;
  float* out_lik    = out + 2 * (size_t)BATCH * NCLS;

  char* ws = (char*)d_ws;
  unsigned short* fbf = (unsigned short*)ws;                                   // 4 MB
  unsigned short* cbf = (unsigned short*)(ws + (size_t)BATCH * FDIM * 2);      // 5 MB
  float* fsq     = (float*)(ws + (size_t)BATCH * FDIM * 2 + (size_t)NCLS * FDIM * 2);
  float* csq     = fsq + BATCH;
  float* lik_row = csq + NCLS;

  prep_kernel<<<(BATCH + NCLS) / 4, 256, 0, stream>>>(feat, centers, fbf, cbf, fsq, csq);
  gemm_kernel<<<(BATCH / BM) * ((NCLS + BN - 1) / BN), 512, 0, stream>>>(
      fbf, cbf, fsq, csq, label, out_logits, out_margin, lik_row);
  lik_reduce_kernel<<<1, 1024, 0, stream>>>(lik_row, out_lik);
}